// Round 13
// baseline (1010.553 us; speedup 1.0000x reference)
//
#include <hip/hip_runtime.h>
#include <stdint.h>

#define T_STEPS 25
#define BB   4096
#define DIN  512
#define DH   1024
#define DOUT 256

typedef float f32x2 __attribute__((ext_vector_type(2)));

struct Keys { uint32_t a[T_STEPS]; uint32_t b[T_STEPS]; };

// Threefry-2x32, exactly as JAX implements it (20 rounds, 5 groups of 4).
__host__ __device__ __forceinline__ void tf2x32(uint32_t k0, uint32_t k1,
                                                uint32_t x0, uint32_t x1,
                                                uint32_t& y0, uint32_t& y1) {
  const uint32_t ks2 = k0 ^ k1 ^ 0x1BD11BDAu;
  x0 += k0; x1 += k1;
#define TFR(r) { x0 += x1; x1 = (x1 << (r)) | (x1 >> (32 - (r))); x1 ^= x0; }
  TFR(13) TFR(15) TFR(26) TFR(6)   x0 += k1;  x1 += ks2 + 1u;
  TFR(17) TFR(29) TFR(16) TFR(24)  x0 += ks2; x1 += k0 + 2u;
  TFR(13) TFR(15) TFR(26) TFR(6)   x0 += k0;  x1 += k1 + 3u;
  TFR(17) TFR(29) TFR(16) TFR(24)  x0 += k1;  x1 += ks2 + 4u;
  TFR(13) TFR(15) TFR(26) TFR(6)   x0 += ks2; x1 += k0 + 5u;
#undef TFR
  y0 = x0; y1 = x1;
}

// Partitionable (modern JAX default) f32 bernoulli keep-bit (verified R5):
__device__ __forceinline__ bool keep_f(uint32_t ka, uint32_t kb, uint32_t e) {
  uint32_t y0, y1;
  tf2x32(ka, kb, 0u, e, y0, y1);
  return (((y0 ^ y1) >> 9) <= 6710886u);
}

// ---- LDS-tiled transpose: in [H][K] -> out [K][H]; H,K multiples of 32.
__global__ __launch_bounds__(256) void k_trt(const float* __restrict__ in,
                                             float* __restrict__ out, int H, int K) {
  __shared__ float tile[32][33];
  const int bh = blockIdx.x * 32, bk = blockIdx.y * 32;
  const int tx = threadIdx.x & 31, ty = threadIdx.x >> 5;   // 32 x 8
#pragma unroll
  for (int r = ty; r < 32; r += 8)
    tile[r][tx] = in[(size_t)(bh + r) * K + bk + tx];
  __syncthreads();
#pragma unroll
  for (int r = ty; r < 32; r += 8)
    out[(size_t)(bk + r) * H + bh + tx] = tile[tx][r];
}

// ---- cur1[b][h] = fma-chain_k(x[b,k]*w1[h,k]) + b1[h], ascending k, single acc.
// v_pk_fma_f32 over h-pairs: two independent IEEE-RN chains per instr -> bit-exact.
__global__ __launch_bounds__(256) void k_cur1s(const float* __restrict__ xT,
                                               const float* __restrict__ w1t,
                                               const float* __restrict__ b1,
                                               float* __restrict__ cur1) {
  const int b  = blockIdx.x * 256 + threadIdx.x;
  const int h0 = blockIdx.y * 32;
  f32x2 acc2[16];
#pragma unroll
  for (int i = 0; i < 16; ++i) acc2[i] = (f32x2){0.f, 0.f};
  for (int k = 0; k < DIN; ++k) {
    float xv = xT[(size_t)k * BB + b];                       // coalesced per-lane
    f32x2 xv2 = {xv, xv};
    const f32x2* wk2 = (const f32x2*)(w1t + (size_t)k * DH + h0);  // wave-uniform
#pragma unroll
    for (int q = 0; q < 16; ++q) {
      f32x2 wv = wk2[q];                                     // -> SGPR pair (s_load)
      asm("v_pk_fma_f32 %0, %2, %1, %0" : "+v"(acc2[q]) : "v"(xv2), "s"(wv));
    }
  }
  float* dst = cur1 + (size_t)b * DH + h0;
#pragma unroll
  for (int i = 0; i < 16; ++i) {
    float2 v;
    v.x = __fadd_rn(acc2[i].x, b1[h0 + i*2 + 0]);
    v.y = __fadd_rn(acc2[i].y, b1[h0 + i*2 + 1]);
    *(float2*)(dst + i*2) = v;
  }
}

// ---- all-25-steps mem1 trajectory (strict f32) + dropout -> bit masks along k.
__global__ __launch_bounds__(256) void k_trajf(const float* __restrict__ cur1,
                                               uint32_t* __restrict__ maskT, Keys kk) {
  const int e = blockIdx.x * 256 + threadIdx.x;    // e = b*1024 + h
  const int lane = threadIdx.x & 63;
  const int b = e >> 10;
  const int w = (e >> 5) & 31;
  const float c = cur1[e];
  float m = 0.0f;
  for (int t = 0; t < T_STEPS; ++t) {
    float r = (m > 1.0f) ? 1.0f : 0.0f;
    m = __fsub_rn(__fadd_rn(__fmul_rn(0.9f, m), c), r);
    bool spk = m > 1.0f;
    bool kp = keep_f(kk.a[t], kk.b[t], (uint32_t)e);
    unsigned long long ball = __ballot(spk && kp);
    if ((lane & 31) == 0)
      maskT[((size_t)t * 32 + w) * BB + b] = (uint32_t)(ball >> (lane & 32));
  }
}

// ---- batched GEMM: 2 rows/thread packed in pk halves, o-tile 32, lanes = rows.
//      cur2[row][o] = fma-chain_k( sel(row,k) * w2t[k][o] ), ascending k.
// acc pair = {rowA, rowB}; weight SGPR pair {w[2q],w[2q+1]} feeds both halves via
// op_sel (even o: lo half of pair; odd o: hi half). Each half is an independent
// IEEE-RN f32 FMA -> per-column chains bit-exact vs reference.
__global__ __launch_bounds__(256, 4) void k_gemm2(const uint32_t* __restrict__ maskT,
                                                  const float* __restrict__ w2t,
                                                  float* __restrict__ cur2) {
  const int t  = blockIdx.x >> 3;                        // block-uniform
  const int b  = ((blockIdx.x & 7) << 8) + threadIdx.x;  // 0..2047 (rowA)
  const int o0 = blockIdx.y * 32;
  const uint32_t* mrow = maskT + (size_t)t * 32 * BB + b;
  f32x2 accp[32];                                        // accp[o] = {rowA, rowB}
#pragma unroll
  for (int i = 0; i < 32; ++i) accp[i] = (f32x2){0.f, 0.f};
  for (int w = 0; w < 32; ++w) {
    const uint32_t wordA = mrow[(size_t)w * BB];          // coalesced
    const uint32_t wordB = mrow[(size_t)w * BB + 2048];   // coalesced
    const float* wp = w2t + (size_t)(w * 32) * DOUT + o0;
#pragma unroll 2
    for (int j = 0; j < 32; ++j) {
      int bmA = ((int)(wordA << (31 - j))) >> 31;         // bit j -> 0 / -1
      int bmB = ((int)(wordB << (31 - j))) >> 31;
      f32x2 sel2;
      sel2.x = __int_as_float(bmA & 0x3FA00000);          // 0.0f or 1.25f (rowA)
      sel2.y = __int_as_float(bmB & 0x3FA00000);          // 0.0f or 1.25f (rowB)
      const f32x2* wk2 = (const f32x2*)(wp + (size_t)j * DOUT);
#pragma unroll
      for (int q = 0; q < 16; ++q) {
        f32x2 wv = wk2[q];                                // -> SGPR pair (s_load)
        // even o = 2q: both halves use w.lo
        asm("v_pk_fma_f32 %0, %1, %2, %0 op_sel:[0,0,0] op_sel_hi:[1,0,1]"
            : "+v"(accp[2*q]) : "v"(sel2), "s"(wv));
        // odd o = 2q+1: both halves use w.hi
        asm("v_pk_fma_f32 %0, %1, %2, %0 op_sel:[0,1,0] op_sel_hi:[1,1,1]"
            : "+v"(accp[2*q+1]) : "v"(sel2), "s"(wv));
      }
    }
  }
  const size_t rowA = (size_t)t * BB + b;
  float* dstA = cur2 + rowA * DOUT + o0;
  float* dstB = cur2 + (rowA + 2048) * DOUT + o0;
#pragma unroll
  for (int q = 0; q < 8; ++q) {
    float4 vA = make_float4(accp[q*4+0].x, accp[q*4+1].x, accp[q*4+2].x, accp[q*4+3].x);
    float4 vB = make_float4(accp[q*4+0].y, accp[q*4+1].y, accp[q*4+2].y, accp[q*4+3].y);
    *(float4*)(dstA + q*4) = vA;
    *(float4*)(dstB + q*4) = vB;
  }
}

// ---- mem2 recursion (strict f32) + sigmoids. cur2 aliases out's second half.
__global__ __launch_bounds__(256) void k_out2(const float* __restrict__ b2,
                                              float* __restrict__ out) {
  const int b = blockIdx.x;
  const int o = threadIdx.x;
  float* out1 = out + (size_t)T_STEPS * BB * DOUT;   // == cur2 region
  const float bb = b2[o];
  float m = 0.0f;
  for (int t = 0; t < T_STEPS; ++t) {
    size_t p = ((size_t)t * BB + b) * DOUT + o;
    float c2 = __fadd_rn(out1[p], bb);
    float r = (m > 1.0f) ? 1.0f : 0.0f;
    m = __fsub_rn(__fadd_rn(__fmul_rn(0.9f, m), c2), r);
    out[p]  = (m > 1.0f) ? 0.7310585786300049f : 0.5f;
    out1[p] = 1.0f / (1.0f + __expf(-m));   // |delta| ~1e-5 << 0.0039 bf16 floor
  }
}

extern "C" void kernel_launch(void* const* d_in, const int* in_sizes, int n_in,
                              void* d_out, int out_size, void* d_ws, size_t ws_size,
                              hipStream_t stream) {
  const float* x  = (const float*)d_in[0];
  const float* w1 = (const float*)d_in[1];
  const float* b1 = (const float*)d_in[2];
  const float* w2 = (const float*)d_in[3];
  const float* b2 = (const float*)d_in[4];
  float* out = (float*)d_out;
  char* ws = (char*)d_ws;

  float*    w1t   = (float*)(ws);                   //  2 MB  [512][1024]
  float*    w2t   = (float*)(ws + 2097152);         //  1 MB  [1024][256]
  float*    xT    = (float*)(ws + 3145728);         //  8 MB  [512][4096]
  float*    cur1  = (float*)(ws + 11534336);        // 16 MB  [4096][1024]
  uint32_t* maskT = (uint32_t*)(ws + 28311552);     // 12.8MB [25][32][4096]
  float*    cur2  = out + (size_t)T_STEPS * BB * DOUT;  // reuse d_out 2nd half

  // partitionable (foldlike) split of key(42): key_t = threefry((0,42),(0,t))
  Keys kk;
  for (int t = 0; t < T_STEPS; ++t) {
    uint32_t y0, y1;
    tf2x32(0u, 42u, 0u, (uint32_t)t, y0, y1);
    kk.a[t] = y0; kk.b[t] = y1;
  }

  k_trt<<<dim3(DH / 32, DIN / 32), 256, 0, stream>>>(w1, w1t, DH, DIN);
  k_trt<<<dim3(DOUT / 32, DH / 32), 256, 0, stream>>>(w2, w2t, DOUT, DH);
  k_trt<<<dim3(BB / 32, DIN / 32), 256, 0, stream>>>(x, xT, BB, DIN);
  k_cur1s<<<dim3(BB / 256, DH / 32), 256, 0, stream>>>(xT, w1t, b1, cur1);
  k_trajf<<<dim3(BB * DH / 256), 256, 0, stream>>>(cur1, maskT, kk);
  k_gemm2<<<dim3(T_STEPS * 8, DOUT / 32), 256, 0, stream>>>(maskT, w2t, cur2);
  k_out2<<<dim3(BB), 256, 0, stream>>>(b2, out);
}

// Round 14
// 912.048 us; speedup vs baseline: 1.1080x; 1.1080x over previous
//
#include <hip/hip_runtime.h>
#include <stdint.h>

#define T_STEPS 25
#define BB   4096
#define DIN  512
#define DH   1024
#define DOUT 256

typedef float f32x2 __attribute__((ext_vector_type(2)));

struct Keys { uint32_t a[T_STEPS]; uint32_t b[T_STEPS]; };

// Threefry-2x32, exactly as JAX implements it (20 rounds, 5 groups of 4).
__host__ __device__ __forceinline__ void tf2x32(uint32_t k0, uint32_t k1,
                                                uint32_t x0, uint32_t x1,
                                                uint32_t& y0, uint32_t& y1) {
  const uint32_t ks2 = k0 ^ k1 ^ 0x1BD11BDAu;
  x0 += k0; x1 += k1;
#define TFR(r) { x0 += x1; x1 = (x1 << (r)) | (x1 >> (32 - (r))); x1 ^= x0; }
  TFR(13) TFR(15) TFR(26) TFR(6)   x0 += k1;  x1 += ks2 + 1u;
  TFR(17) TFR(29) TFR(16) TFR(24)  x0 += ks2; x1 += k0 + 2u;
  TFR(13) TFR(15) TFR(26) TFR(6)   x0 += k0;  x1 += k1 + 3u;
  TFR(17) TFR(29) TFR(16) TFR(24)  x0 += k1;  x1 += ks2 + 4u;
  TFR(13) TFR(15) TFR(26) TFR(6)   x0 += ks2; x1 += k0 + 5u;
#undef TFR
  y0 = x0; y1 = x1;
}

// Partitionable (modern JAX default) f32 bernoulli keep-bit (verified R5):
__device__ __forceinline__ bool keep_f(uint32_t ka, uint32_t kb, uint32_t e) {
  uint32_t y0, y1;
  tf2x32(ka, kb, 0u, e, y0, y1);
  return (((y0 ^ y1) >> 9) <= 6710886u);
}

// ---- LDS-tiled transpose: in [H][K] -> out [K][H]; H,K multiples of 32.
__global__ __launch_bounds__(256) void k_trt(const float* __restrict__ in,
                                             float* __restrict__ out, int H, int K) {
  __shared__ float tile[32][33];
  const int bh = blockIdx.x * 32, bk = blockIdx.y * 32;
  const int tx = threadIdx.x & 31, ty = threadIdx.x >> 5;   // 32 x 8
#pragma unroll
  for (int r = ty; r < 32; r += 8)
    tile[r][tx] = in[(size_t)(bh + r) * K + bk + tx];
  __syncthreads();
#pragma unroll
  for (int r = ty; r < 32; r += 8)
    out[(size_t)(bk + r) * H + bh + tx] = tile[tx][r];
}

// ---- FUSED cur1 + trajectory + mask build.
// Thread owns (b, h0..h0+31): 32 fma-chains (ascending k, single acc, pk-paired),
// then 25-step strict-f32 mem1 dynamics + threefry dropout. Its 32 h's form
// exactly one mask word -> per-thread bit pack, no ballot, coalesced writes.
__global__ __launch_bounds__(256) void k_fused(const float* __restrict__ xT,
                                               const float* __restrict__ w1t,
                                               const float* __restrict__ b1,
                                               uint32_t* __restrict__ maskT, Keys kk) {
  const int b  = blockIdx.x * 256 + threadIdx.x;
  const int h0 = blockIdx.y * 32;
  f32x2 acc2[16];
#pragma unroll
  for (int i = 0; i < 16; ++i) acc2[i] = (f32x2){0.f, 0.f};
  for (int k = 0; k < DIN; ++k) {
    float xv = xT[(size_t)k * BB + b];                       // coalesced per-lane
    f32x2 xv2 = {xv, xv};
    const f32x2* wk2 = (const f32x2*)(w1t + (size_t)k * DH + h0);  // wave-uniform
#pragma unroll
    for (int q = 0; q < 16; ++q) {
      f32x2 wv = wk2[q];                                     // -> SGPR pair (s_load)
      asm("v_pk_fma_f32 %0, %2, %1, %0" : "+v"(acc2[q]) : "v"(xv2), "s"(wv));
    }
  }
  float cur[32], m[32];
#pragma unroll
  for (int i = 0; i < 16; ++i) {
    cur[i*2+0] = __fadd_rn(acc2[i].x, b1[h0 + i*2 + 0]);
    cur[i*2+1] = __fadd_rn(acc2[i].y, b1[h0 + i*2 + 1]);
    m[i*2+0] = 0.0f; m[i*2+1] = 0.0f;
  }
  const uint32_t e0 = (uint32_t)(b * DH + h0);
  uint32_t* mdst = maskT + (size_t)(h0 >> 5) * BB + b;
  for (int t = 0; t < T_STEPS; ++t) {
    uint32_t word = 0;
    const uint32_t ka = kk.a[t], kb = kk.b[t];
#pragma unroll
    for (int i = 0; i < 32; ++i) {
      float r = (m[i] > 1.0f) ? 1.0f : 0.0f;
      m[i] = __fsub_rn(__fadd_rn(__fmul_rn(0.9f, m[i]), cur[i]), r);
      bool spk = m[i] > 1.0f;
      bool kp = keep_f(ka, kb, e0 + i);
      word |= (uint32_t)(spk && kp) << i;
    }
    mdst[(size_t)t * 32 * BB] = word;                        // coalesced across lanes
  }
}

// ---- batched GEMM (R12-proven structure + mask-word prefetch), o-tile 32:
//      cur2[row][o] = fma-chain_k( sel(row,k) * w2t[k][o] ), ascending k.
// Weights forced to SGPR pairs ("s" -> s_load, scalar pipe); sel in {0,1.25f}.
// Each pk_fma = two independent IEEE-RN f32 FMAs -> per-column chains bit-exact.
__global__ __launch_bounds__(256) void k_gemm2(const uint32_t* __restrict__ maskT,
                                               const float* __restrict__ w2t,
                                               float* __restrict__ cur2) {
  const int row = blockIdx.x * 256 + threadIdx.x;  // flat t*4096+b; t block-uniform
  const int t = row >> 12, b = row & 4095;
  const int o0 = blockIdx.y * 32;
  const uint32_t* mrow = maskT + (size_t)t * 32 * BB + b;
  f32x2 acc2[16];
#pragma unroll
  for (int i = 0; i < 16; ++i) acc2[i] = (f32x2){0.f, 0.f};
  uint32_t word = mrow[0];                         // pipeline head
  for (int w = 0; w < 32; ++w) {
    const uint32_t wnext = (w < 31) ? mrow[(size_t)(w + 1) * BB] : 0u;  // prefetch
    const float* wp = w2t + (size_t)(w * 32) * DOUT + o0;
#pragma unroll 2
    for (int j = 0; j < 32; ++j) {
      int bm = ((int)(word << (31 - j))) >> 31;            // bit j -> 0 / -1
      float sel = __int_as_float(bm & 0x3FA00000);         // 0.0f or 1.25f
      f32x2 sel2 = {sel, sel};
      const f32x2* wk2 = (const f32x2*)(wp + (size_t)j * DOUT);
#pragma unroll
      for (int q = 0; q < 16; ++q) {
        f32x2 wv = wk2[q];                                 // -> SGPR pair (s_load)
        asm("v_pk_fma_f32 %0, %2, %1, %0" : "+v"(acc2[q]) : "v"(sel2), "s"(wv));
      }
    }
    word = wnext;
  }
  float* dst = cur2 + (size_t)row * DOUT + o0;
#pragma unroll
  for (int q = 0; q < 4; ++q) {
    float4 v0 = make_float4(acc2[q*4+0].x, acc2[q*4+0].y, acc2[q*4+1].x, acc2[q*4+1].y);
    float4 v1 = make_float4(acc2[q*4+2].x, acc2[q*4+2].y, acc2[q*4+3].x, acc2[q*4+3].y);
    *(float4*)(dst + q*8)     = v0;
    *(float4*)(dst + q*8 + 4) = v1;
  }
}

// ---- mem2 recursion (strict f32) + sigmoids. cur2 aliases out's second half.
__global__ __launch_bounds__(256) void k_out2(const float* __restrict__ b2,
                                              float* __restrict__ out) {
  const int b = blockIdx.x;
  const int o = threadIdx.x;
  float* out1 = out + (size_t)T_STEPS * BB * DOUT;   // == cur2 region
  const float bb = b2[o];
  float m = 0.0f;
  for (int t = 0; t < T_STEPS; ++t) {
    size_t p = ((size_t)t * BB + b) * DOUT + o;
    float c2 = __fadd_rn(out1[p], bb);
    float r = (m > 1.0f) ? 1.0f : 0.0f;
    m = __fsub_rn(__fadd_rn(__fmul_rn(0.9f, m), c2), r);
    out[p]  = (m > 1.0f) ? 0.7310585786300049f : 0.5f;
    out1[p] = 1.0f / (1.0f + __expf(-m));   // |delta| ~1e-5 << 0.0039 bf16 floor
  }
}

extern "C" void kernel_launch(void* const* d_in, const int* in_sizes, int n_in,
                              void* d_out, int out_size, void* d_ws, size_t ws_size,
                              hipStream_t stream) {
  const float* x  = (const float*)d_in[0];
  const float* w1 = (const float*)d_in[1];
  const float* b1 = (const float*)d_in[2];
  const float* w2 = (const float*)d_in[3];
  const float* b2 = (const float*)d_in[4];
  float* out = (float*)d_out;
  char* ws = (char*)d_ws;

  float*    w1t   = (float*)(ws);                   //  2 MB  [512][1024]
  float*    w2t   = (float*)(ws + 2097152);         //  1 MB  [1024][256]
  float*    xT    = (float*)(ws + 3145728);         //  8 MB  [512][4096]
  uint32_t* maskT = (uint32_t*)(ws + 11534336);     // 12.8MB [25][32][4096]
  float*    cur2  = out + (size_t)T_STEPS * BB * DOUT;  // reuse d_out 2nd half

  // partitionable (foldlike) split of key(42): key_t = threefry((0,42),(0,t))
  Keys kk;
  for (int t = 0; t < T_STEPS; ++t) {
    uint32_t y0, y1;
    tf2x32(0u, 42u, 0u, (uint32_t)t, y0, y1);
    kk.a[t] = y0; kk.b[t] = y1;
  }

  k_trt<<<dim3(DH / 32, DIN / 32), 256, 0, stream>>>(w1, w1t, DH, DIN);
  k_trt<<<dim3(DOUT / 32, DH / 32), 256, 0, stream>>>(w2, w2t, DOUT, DH);
  k_trt<<<dim3(BB / 32, DIN / 32), 256, 0, stream>>>(x, xT, BB, DIN);
  k_fused<<<dim3(BB / 256, DH / 32), 256, 0, stream>>>(xT, w1t, b1, maskT, kk);
  k_gemm2<<<dim3(T_STEPS * BB / 256, DOUT / 32), 256, 0, stream>>>(maskT, w2t, cur2);
  k_out2<<<dim3(BB), 256, 0, stream>>>(b2, out);
}